// Round 1
// baseline (1122.107 us; speedup 1.0000x reference)
//
#include <hip/hip_runtime.h>
#include <hip/hip_bf16.h>
#include <math.h>

// ---------------------------------------------------------------------------
// VAR quantizer forward: 10 scales, per scale:
//   rest = area_downsample(f_rest)        (skip at last scale)
//   idx  = argmin_v ||rest_row - emb_v||^2
//   h    = emb[idx]; h = bicubic_up(h)    (skip at last scale)
//   h    = 0.5*h + 0.5*(conv3x3(h,W[k]) + b[k])
//   f_hat += h; f_rest -= h; loss += 1.25*mean((f_hat-f)^2)
// Output: [f_hat 1048576][loss 1][idx-as-float 87040]
// ---------------------------------------------------------------------------

#define B_  128
#define C_  32
#define H_  16
#define V_  4096
#define SN_ 10
#define NPIX_ (B_*C_*H_*H_)   // 1048576

// ws layout (float offsets)
#define WS_FREST   0
#define WS_FHAT    1048576
#define WS_RESTS   2097152
#define WS_HSMALL  3145728
#define WS_HUP     4194304
#define WS_ESQ     5242880
#define WS_PDIST   5246976
#define WS_PIDX    5312512
#define WS_IDXINT  5378048
#define WS_TW      5410816
#define WS_TI      5411392
#define WS_LOSSP   5411968
// total 5422208 floats = ~20.7 MB

// --------------------------- init kernels ----------------------------------

__global__ __launch_bounds__(256) void k_init(const float* __restrict__ f,
                                              float* __restrict__ f_rest,
                                              float* __restrict__ f_hat) {
  int g = blockIdx.x * 256 + threadIdx.x;            // 1024 blocks -> 262144 float4
  float4 v = ((const float4*)f)[g];
  ((float4*)f_rest)[g] = v;
  ((float4*)f_hat)[g] = make_float4(0.f, 0.f, 0.f, 0.f);
}

__global__ __launch_bounds__(256) void k_esq(const float* __restrict__ emb,
                                             float* __restrict__ esq) {
  int v = blockIdx.x * 256 + threadIdx.x;            // 16 blocks -> 4096
  const float4* e4 = (const float4*)(emb + (size_t)v * 32);
  float s = 0.f;
#pragma unroll
  for (int q = 0; q < 8; ++q) {
    float4 x = e4[q];
    s += x.x * x.x + x.y * x.y + x.z * x.z + x.w * x.w;
  }
  esq[v] = s;
}

// bicubic 4-tap tables for scales 0..8, computed in f64 like the numpy code
__global__ void k_taps(float* __restrict__ tw, int* __restrict__ ti) {
  int t = threadIdx.x;
  if (t >= 144) return;
  const int pns[9] = {1, 2, 3, 4, 5, 6, 8, 10, 13};
  int si = t / 16, Y = t % 16;
  int pn = pns[si];
  double src = (Y + 0.5) * (double)pn / 16.0 - 0.5;
  double fl = floor(src);
  const double a = -0.75;
#pragma unroll
  for (int k = 0; k < 4; ++k) {
    double x = fabs(src - (fl + (k - 1)));
    double w;
    if (x <= 1.0)      w = (a + 2.0) * x * x * x - (a + 3.0) * x * x + 1.0;
    else if (x < 2.0)  w = a * x * x * x - 5.0 * a * x * x + 8.0 * a * x - 4.0 * a;
    else               w = 0.0;
    int id = (int)fl + (k - 1);
    id = id < 0 ? 0 : (id > pn - 1 ? pn - 1 : id);
    tw[si * 64 + Y * 4 + k] = (float)w;
    ti[si * 64 + Y * 4 + k] = id;
  }
}

// --------------------------- per-scale kernels -----------------------------

// area downsample f_rest [B,C,16,16] -> out [B,C,pn,pn]
__global__ __launch_bounds__(256) void k_down(const float* __restrict__ fr,
                                              float* __restrict__ out,
                                              int pn, int total) {
  int tid = blockIdx.x * 256 + threadIdx.x;
  if (tid >= total) return;
  int x = tid % pn;
  int y = (tid / pn) % pn;
  int bc = tid / (pn * pn);
  int sy = (y * 16) / pn, ey = ((y + 1) * 16 + pn - 1) / pn;
  int sx = (x * 16) / pn, ex = ((x + 1) * 16 + pn - 1) / pn;
  const float* base = fr + (size_t)bc * 256;
  float s = 0.f;
  for (int yy = sy; yy < ey; ++yy)
    for (int xx = sx; xx < ex; ++xx) s += base[yy * 16 + xx];
  out[tid] = s * ((1.0f / (float)(ey - sy)) * (1.0f / (float)(ex - sx)));
}

// NN search: block = 64 rows x (cps codes of this split). 4x4 register tile.
__global__ __launch_bounds__(256) void k_nn(const float* __restrict__ rest,
                                            const float* __restrict__ emb,
                                            const float* __restrict__ esq,
                                            float* __restrict__ pdist,
                                            int* __restrict__ pidx,
                                            int pn2, int cps, int split) {
  __shared__ float As[64 * 32];
  __shared__ float Bs[64 * 32];
  __shared__ float Es[64];
  __shared__ float Rd[64 * 16];
  __shared__ int   Ri[64 * 16];
  int t = threadIdx.x;
  int rb = blockIdx.x, sp = blockIdx.y;

  // stage A tile: 64 rows x 32 channels (XOR-swizzled quads, row stride 32)
  {
    int r = t >> 2;
    int c0 = (t & 3) * 8;
    int n = rb * 64 + r;
    int b = n / pn2, rem = n % pn2;
    const float* src = rest + (size_t)b * 32 * pn2 + rem;
    float v[8];
#pragma unroll
    for (int j = 0; j < 8; ++j) v[j] = src[(size_t)(c0 + j) * pn2];
    int swz = (r >> 2) & 7;
    float4* As4 = (float4*)As;
    int kq0 = c0 >> 2;
    As4[r * 8 + (kq0 ^ swz)]       = make_float4(v[0], v[1], v[2], v[3]);
    As4[r * 8 + ((kq0 + 1) ^ swz)] = make_float4(v[4], v[5], v[6], v[7]);
  }

  int tx = t & 15, ty = t >> 4;
  float best[4];
  int bidx[4];
#pragma unroll
  for (int i = 0; i < 4; ++i) { best[i] = 3.4e38f; bidx[i] = 0x7fffffff; }
  int swzA = ty & 7;
  int swzB = tx & 7;
  int ntiles = cps >> 6;

  for (int tile = 0; tile < ntiles; ++tile) {
    int vbase = sp * cps + tile * 64;
    __syncthreads();
    {
      int r = t >> 2;
      int kq0 = (t & 3) * 2;
      const float4* e4 = (const float4*)(emb + (size_t)(vbase + r) * 32);
      int swz = (r >> 2) & 7;
      float4* Bs4 = (float4*)Bs;
      Bs4[r * 8 + (kq0 ^ swz)]       = e4[kq0];
      Bs4[r * 8 + ((kq0 + 1) ^ swz)] = e4[kq0 + 1];
      if (t < 64) Es[t] = esq[vbase + t];
    }
    __syncthreads();

    float acc[4][4];
#pragma unroll
    for (int i = 0; i < 4; ++i)
#pragma unroll
      for (int j = 0; j < 4; ++j) acc[i][j] = 0.f;

    const float4* As4 = (const float4*)As;
    const float4* Bs4 = (const float4*)Bs;
#pragma unroll
    for (int kq = 0; kq < 8; ++kq) {
      float4 a[4], b[4];
#pragma unroll
      for (int i = 0; i < 4; ++i) a[i] = As4[(ty * 4 + i) * 8 + (kq ^ swzA)];
#pragma unroll
      for (int j = 0; j < 4; ++j) b[j] = Bs4[(tx * 4 + j) * 8 + (kq ^ swzB)];
#pragma unroll
      for (int i = 0; i < 4; ++i)
#pragma unroll
        for (int j = 0; j < 4; ++j)
          acc[i][j] += a[i].x * b[j].x + a[i].y * b[j].y +
                       a[i].z * b[j].z + a[i].w * b[j].w;
    }
#pragma unroll
    for (int j = 0; j < 4; ++j) {
      int code = vbase + tx * 4 + j;
      float es = Es[tx * 4 + j];
#pragma unroll
      for (int i = 0; i < 4; ++i) {
        float d = es - 2.0f * acc[i][j];
        if (d < best[i]) { best[i] = d; bidx[i] = code; }
      }
    }
  }

  __syncthreads();
#pragma unroll
  for (int i = 0; i < 4; ++i) {
    Rd[(ty * 4 + i) * 16 + tx] = best[i];
    Ri[(ty * 4 + i) * 16 + tx] = bidx[i];
  }
  __syncthreads();
  if (t < 64) {
    float bd = Rd[t * 16];
    int bi = Ri[t * 16];
#pragma unroll
    for (int x = 1; x < 16; ++x) {
      float d = Rd[t * 16 + x];
      int ii = Ri[t * 16 + x];
      if (d < bd || (d == bd && ii < bi)) { bd = d; bi = ii; }
    }
    size_t row = (size_t)rb * 64 + t;
    pdist[row * split + sp] = bd;
    pidx[row * split + sp] = bi;
  }
}

__global__ __launch_bounds__(256) void k_combine(const float* __restrict__ pdist,
                                                 const int* __restrict__ pidx,
                                                 int rows, int split,
                                                 float* __restrict__ out_idx_f,
                                                 int* __restrict__ idx_int) {
  int n = blockIdx.x * 256 + threadIdx.x;
  if (n >= rows) return;
  float bd = pdist[(size_t)n * split];
  int bi = pidx[(size_t)n * split];
  for (int s = 1; s < split; ++s) {
    float d = pdist[(size_t)n * split + s];
    int ii = pidx[(size_t)n * split + s];
    if (d < bd || (d == bd && ii < bi)) { bd = d; bi = ii; }
  }
  out_idx_f[n] = (float)bi;
  idx_int[n] = bi;
}

__global__ __launch_bounds__(256) void k_gather(const float* __restrict__ emb,
                                                const int* __restrict__ idx_int,
                                                float* __restrict__ h_small,
                                                int pn2, int total) {
  int tid = blockIdx.x * 256 + threadIdx.x;
  if (tid >= total) return;
  int n = tid >> 5, c = tid & 31;
  int b = n / pn2, rem = n % pn2;
  h_small[((size_t)b * 32 + c) * pn2 + rem] = emb[(size_t)idx_int[n] * 32 + c];
}

// bicubic upsample [B,C,pn,pn] -> [B,C,16,16] via 4-tap tables
__global__ __launch_bounds__(256) void k_up(const float* __restrict__ hs,
                                            float* __restrict__ hu,
                                            const float* __restrict__ tw,
                                            const int* __restrict__ ti,
                                            int pn, int si) {
  int tid = blockIdx.x * 256 + threadIdx.x;  // NPIX_ total
  int X = tid & 15, Y = (tid >> 4) & 15;
  int bc = tid >> 8;
  const float* w = tw + si * 64;
  const int* ix = ti + si * 64;
  const float* src = hs + (size_t)bc * pn * pn;
  float wx[4]; int ixx[4];
#pragma unroll
  for (int u = 0; u < 4; ++u) { wx[u] = w[X * 4 + u]; ixx[u] = ix[X * 4 + u]; }
  float acc = 0.f;
#pragma unroll
  for (int tt = 0; tt < 4; ++tt) {
    float wy = w[Y * 4 + tt];
    int iy = ix[Y * 4 + tt];
    const float* rowp = src + iy * pn;
    float r = 0.f;
#pragma unroll
    for (int u = 0; u < 4; ++u) r += wx[u] * rowp[ixx[u]];
    acc += wy * r;
  }
  hu[tid] = acc;
}

// 3x3 SAME conv (32->32) + residual mix; fused f_hat += out, f_rest -= out.
// grid (B, 4): 8 output channels per block. Weights read via uniform (scalar) loads.
__global__ __launch_bounds__(256) void k_conv(const float* __restrict__ h,
                                              const float* __restrict__ W,
                                              const float* __restrict__ bias,
                                              float* __restrict__ f_hat,
                                              float* __restrict__ f_rest) {
  __shared__ float in_s[32 * 256];
  int b = blockIdx.x, cog = blockIdx.y * 8;
  int t = threadIdx.x;
  const float4* h4 = (const float4*)(h + (size_t)b * 32 * 256);
  float4* in4 = (float4*)in_s;
  for (int i = t; i < 32 * 64; i += 256) in4[i] = h4[i];
  __syncthreads();

  int X = t & 15, Y = t >> 4;
  float acc[8];
#pragma unroll
  for (int o = 0; o < 8; ++o) acc[o] = bias[cog + o];

  for (int ci = 0; ci < 32; ++ci) {
    float in9[9];
#pragma unroll
    for (int dy = 0; dy < 3; ++dy)
#pragma unroll
      for (int dx = 0; dx < 3; ++dx) {
        int yy = Y + dy - 1, xx = X + dx - 1;
        in9[dy * 3 + dx] = (yy >= 0 && yy < 16 && xx >= 0 && xx < 16)
                               ? in_s[ci * 256 + yy * 16 + xx] : 0.f;
      }
    const float* wp = W + ((size_t)cog * 32 + ci) * 9;
#pragma unroll
    for (int o = 0; o < 8; ++o) {
      const float* w9 = wp + (size_t)o * 32 * 9;
#pragma unroll
      for (int q = 0; q < 9; ++q) acc[o] += w9[q] * in9[q];
    }
  }
#pragma unroll
  for (int o = 0; o < 8; ++o) {
    size_t oidx = ((size_t)b * 32 + cog + o) * 256 + t;
    float out = 0.5f * in_s[(cog + o) * 256 + t] + 0.5f * acc[o];
    f_hat[oidx] += out;
    f_rest[oidx] -= out;
  }
}

// per-scale loss partial sums: 1024 blocks, block partial of (f_hat-f)^2
__global__ __launch_bounds__(256) void k_loss(const float* __restrict__ f_hat,
                                              const float* __restrict__ f,
                                              float* __restrict__ part) {
  int t = threadIdx.x;
  int g = blockIdx.x * 256 + t;
  float4 x = ((const float4*)f_hat)[g];
  float4 y = ((const float4*)f)[g];
  float d0 = x.x - y.x, d1 = x.y - y.y, d2 = x.z - y.z, d3 = x.w - y.w;
  float s = d0 * d0 + d1 * d1 + d2 * d2 + d3 * d3;
  __shared__ float red[256];
  red[t] = s;
  __syncthreads();
  for (int o = 128; o > 0; o >>= 1) {
    if (t < o) red[t] += red[t + o];
    __syncthreads();
  }
  if (t == 0) part[blockIdx.x] = red[0];
}

__global__ __launch_bounds__(256) void k_copy(const float* __restrict__ f_hat,
                                              float* __restrict__ out) {
  int g = blockIdx.x * 256 + threadIdx.x;
  ((float4*)out)[g] = ((const float4*)f_hat)[g];
}

__global__ __launch_bounds__(256) void k_lossfin(const float* __restrict__ part,
                                                 float* __restrict__ out) {
  int t = threadIdx.x;
  float s = 0.f;
  for (int i = t; i < SN_ * 1024; i += 256) s += part[i];
  __shared__ float red[256];
  red[t] = s;
  __syncthreads();
  for (int o = 128; o > 0; o >>= 1) {
    if (t < o) red[t] += red[t + o];
    __syncthreads();
  }
  if (t == 0) out[NPIX_] = red[0] * (1.25f / (10.0f * (float)NPIX_));
}

// --------------------------- host side -------------------------------------

// replicate np.linspace + np.argmin(np.abs(ticks - si/9)) bit-exactly in f64
static void compute_phi_k(int* ks) {
  const int K = 4;
  double start = 1.0 / (3.0 * K);
  double stop = 1.0 - 1.0 / (3.0 * K);
  double step = (stop - start) / (K - 1);
  double ticks[4];
  for (int i = 0; i < K; ++i) ticks[i] = (double)i * step + start;
  ticks[K - 1] = stop;
  for (int si = 0; si < SN_; ++si) {
    double x = (double)si / (SN_ - 1);
    int best = 0;
    double bd = fabs(ticks[0] - x);
    for (int i = 1; i < K; ++i) {
      double d = fabs(ticks[i] - x);
      if (d < bd) { bd = d; best = i; }
    }
    ks[si] = best;
  }
}

extern "C" void kernel_launch(void* const* d_in, const int* in_sizes, int n_in,
                              void* d_out, int out_size, void* d_ws, size_t ws_size,
                              hipStream_t stream) {
  (void)in_sizes; (void)n_in; (void)out_size; (void)ws_size;
  const float* f    = (const float*)d_in[0];
  const float* emb  = (const float*)d_in[1];
  const float* phiW = (const float*)d_in[2];
  const float* phiB = (const float*)d_in[3];
  float* out = (float*)d_out;
  float* ws = (float*)d_ws;

  float* f_rest = ws + WS_FREST;
  float* f_hat  = ws + WS_FHAT;
  float* rest_s = ws + WS_RESTS;
  float* h_sm   = ws + WS_HSMALL;
  float* h_up   = ws + WS_HUP;
  float* esq    = ws + WS_ESQ;
  float* pdist  = ws + WS_PDIST;
  int*   pidx   = (int*)(ws + WS_PIDX);
  int*   idxint = (int*)(ws + WS_IDXINT);
  float* tw     = ws + WS_TW;
  int*   ti     = (int*)(ws + WS_TI);
  float* lossp  = ws + WS_LOSSP;

  static const int pns[SN_]    = {1, 2, 3, 4, 5, 6, 8, 10, 13, 16};
  static const int splits[SN_] = {64, 32, 16, 16, 8, 8, 4, 2, 2, 1};
  int ks[SN_];
  compute_phi_k(ks);

  k_init<<<1024, 256, 0, stream>>>(f, f_rest, f_hat);
  k_esq<<<16, 256, 0, stream>>>(emb, esq);
  k_taps<<<1, 256, 0, stream>>>(tw, ti);

  int idx_off = 0;
  for (int si = 0; si < SN_; ++si) {
    int pn = pns[si];
    int pn2 = pn * pn;
    int rows = B_ * pn2;
    int split = splits[si];
    int cps = V_ / split;
    const float* rest = (si < SN_ - 1) ? rest_s : f_rest;

    if (si < SN_ - 1) {
      int total = B_ * C_ * pn2;
      k_down<<<(total + 255) / 256, 256, 0, stream>>>(f_rest, rest_s, pn, total);
    }

    k_nn<<<dim3(rows / 64, split), 256, 0, stream>>>(rest, emb, esq, pdist, pidx,
                                                     (si < SN_ - 1) ? pn2 : 256, cps, split);
    k_combine<<<(rows + 255) / 256, 256, 0, stream>>>(pdist, pidx, rows, split,
                                                      out + NPIX_ + 1 + idx_off, idxint);
    k_gather<<<(rows * 32 + 255) / 256, 256, 0, stream>>>(emb, idxint, h_sm,
                                                          (si < SN_ - 1) ? pn2 : 256, rows * 32);
    if (si < SN_ - 1)
      k_up<<<NPIX_ / 256, 256, 0, stream>>>(h_sm, h_up, tw, ti, pn, si);

    const float* hin = (si < SN_ - 1) ? h_up : h_sm;
    k_conv<<<dim3(B_, 4), 256, 0, stream>>>(hin, phiW + (size_t)ks[si] * 32 * 32 * 9,
                                            phiB + (size_t)ks[si] * 32, f_hat, f_rest);
    k_loss<<<1024, 256, 0, stream>>>(f_hat, f, lossp + si * 1024);
    idx_off += rows;
  }

  k_copy<<<1024, 256, 0, stream>>>(f_hat, out);
  k_lossfin<<<1, 256, 0, stream>>>(lossp, out);
}

// Round 2
// 714.827 us; speedup vs baseline: 1.5698x; 1.5698x over previous
//
#include <hip/hip_runtime.h>
#include <hip/hip_bf16.h>
#include <math.h>

// ---------------------------------------------------------------------------
// VAR quantizer forward. Round 2: MFMA-based NN search (3-way bf16 split for
// f32-class accuracy), argmin folded into MFMA accumulator init (C = -esq/2),
// double-buffered emb staging via global_load_lds, conv+loss fusion.
// Output: [f_hat 1048576][loss 1][idx-as-float 87040]
// ---------------------------------------------------------------------------

#define B_  128
#define C_  32
#define H_  16
#define V_  4096
#define SN_ 10
#define NPIX_ (B_*C_*H_*H_)   // 1048576

// ws layout (float offsets)
#define WS_FREST   0
#define WS_FHAT    1048576
#define WS_HSM     2097152
#define WS_HUP     3145728            // aliased: pdist[131072], pidx[131072]
#define WS_ESQ     4194304
#define WS_TW      4198400
#define WS_TI      4198976
#define WS_LOSSP   4199552
#define WS_RESTH   4204672            // ushort[1048576]
#define WS_RESTM   4728960
#define WS_RESTL   5253248
#define WS_EMBH    5777536            // ushort[131072]
#define WS_EMBM    5843072
#define WS_EMBL    5908608
// end 5974144 floats = 22.9 MB

typedef __attribute__((ext_vector_type(8))) short short8_t;
typedef __attribute__((ext_vector_type(4))) float f32x4;
#define MFMA(a,b,c) __builtin_amdgcn_mfma_f32_16x16x32_bf16((a),(b),(c),0,0,0)

__device__ inline void gl_lds16(const void* g, void* l) {
  __builtin_amdgcn_global_load_lds((const __attribute__((address_space(1))) void*)g,
                                   (__attribute__((address_space(3))) void*)l, 16, 0, 0);
}
__device__ inline void gl_lds4(const void* g, void* l) {
  __builtin_amdgcn_global_load_lds((const __attribute__((address_space(1))) void*)g,
                                   (__attribute__((address_space(3))) void*)l, 4, 0, 0);
}

// split f32 -> 3 truncated bf16 levels (hi + mid + lo captures ~24 bits)
__device__ inline void split3(float a, ushort* h, ushort* m, ushort* l) {
  unsigned ua = __float_as_uint(a);
  ushort uh = (ushort)(ua >> 16);
  float fh = __uint_as_float((unsigned)uh << 16);
  float r1 = a - fh;
  ushort um = (ushort)(__float_as_uint(r1) >> 16);
  float fm = __uint_as_float((unsigned)um << 16);
  float r2 = r1 - fm;
  ushort ul = (ushort)(__float_as_uint(r2) >> 16);
  *h = uh; *m = um; *l = ul;
}

// --------------------------- init kernels ----------------------------------

__global__ __launch_bounds__(256) void k_init(const float* __restrict__ f,
                                              float* __restrict__ f_rest,
                                              float* __restrict__ f_hat) {
  int g = blockIdx.x * 256 + threadIdx.x;
  float4 v = ((const float4*)f)[g];
  ((float4*)f_rest)[g] = v;
  ((float4*)f_hat)[g] = make_float4(0.f, 0.f, 0.f, 0.f);
}

// emb: esq + 3-level bf16 split
__global__ __launch_bounds__(256) void k_esplit(const float* __restrict__ emb,
                                                float* __restrict__ esq,
                                                ushort* __restrict__ eh,
                                                ushort* __restrict__ em,
                                                ushort* __restrict__ el) {
  int v = blockIdx.x * 256 + threadIdx.x;   // 16 blocks -> 4096
  const float4* e4 = (const float4*)(emb + (size_t)v * 32);
  float s = 0.f;
#pragma unroll
  for (int half = 0; half < 4; ++half) {
    float4 x0 = e4[half * 2], x1 = e4[half * 2 + 1];
    s += x0.x * x0.x + x0.y * x0.y + x0.z * x0.z + x0.w * x0.w;
    s += x1.x * x1.x + x1.y * x1.y + x1.z * x1.z + x1.w * x1.w;
    float xs[8] = {x0.x, x0.y, x0.z, x0.w, x1.x, x1.y, x1.z, x1.w};
    ushort hs[8], ms[8], ls[8];
#pragma unroll
    for (int j = 0; j < 8; ++j) split3(xs[j], &hs[j], &ms[j], &ls[j]);
    uint4 ph, pm, pl;
    ph.x = (unsigned)hs[0] | ((unsigned)hs[1] << 16); ph.y = (unsigned)hs[2] | ((unsigned)hs[3] << 16);
    ph.z = (unsigned)hs[4] | ((unsigned)hs[5] << 16); ph.w = (unsigned)hs[6] | ((unsigned)hs[7] << 16);
    pm.x = (unsigned)ms[0] | ((unsigned)ms[1] << 16); pm.y = (unsigned)ms[2] | ((unsigned)ms[3] << 16);
    pm.z = (unsigned)ms[4] | ((unsigned)ms[5] << 16); pm.w = (unsigned)ms[6] | ((unsigned)ms[7] << 16);
    pl.x = (unsigned)ls[0] | ((unsigned)ls[1] << 16); pl.y = (unsigned)ls[2] | ((unsigned)ls[3] << 16);
    pl.z = (unsigned)ls[4] | ((unsigned)ls[5] << 16); pl.w = (unsigned)ls[6] | ((unsigned)ls[7] << 16);
    ((uint4*)(eh + (size_t)v * 32))[half] = ph;
    ((uint4*)(em + (size_t)v * 32))[half] = pm;
    ((uint4*)(el + (size_t)v * 32))[half] = pl;
  }
  esq[v] = s;
}

__global__ void k_taps(float* __restrict__ tw, int* __restrict__ ti) {
  int t = threadIdx.x;
  if (t >= 144) return;
  const int pns[9] = {1, 2, 3, 4, 5, 6, 8, 10, 13};
  int si = t / 16, Y = t % 16;
  int pn = pns[si];
  double src = (Y + 0.5) * (double)pn / 16.0 - 0.5;
  double fl = floor(src);
  const double a = -0.75;
#pragma unroll
  for (int k = 0; k < 4; ++k) {
    double x = fabs(src - (fl + (k - 1)));
    double w;
    if (x <= 1.0)      w = (a + 2.0) * x * x * x - (a + 3.0) * x * x + 1.0;
    else if (x < 2.0)  w = a * x * x * x - 5.0 * a * x * x + 8.0 * a * x - 4.0 * a;
    else               w = 0.0;
    int id = (int)fl + (k - 1);
    id = id < 0 ? 0 : (id > pn - 1 ? pn - 1 : id);
    tw[si * 64 + Y * 4 + k] = (float)w;
    ti[si * 64 + Y * 4 + k] = id;
  }
}

// --------------------------- per-scale kernels -----------------------------

// area downsample -> [n][c] 3-level bf16
__global__ __launch_bounds__(256) void k_down3(const float* __restrict__ fr,
                                               ushort* __restrict__ rh,
                                               ushort* __restrict__ rm,
                                               ushort* __restrict__ rl,
                                               int pn, int total) {
  int tid = blockIdx.x * 256 + threadIdx.x;
  if (tid >= total) return;
  int c = tid & 31, n = tid >> 5;
  int pn2 = pn * pn;
  int b = n / pn2, rem = n % pn2;
  int y = rem / pn, x = rem % pn;
  int sy = (y * 16) / pn, ey = ((y + 1) * 16 + pn - 1) / pn;
  int sx = (x * 16) / pn, ex = ((x + 1) * 16 + pn - 1) / pn;
  const float* base = fr + ((size_t)b * 32 + c) * 256;
  float s = 0.f;
  for (int yy = sy; yy < ey; ++yy)
    for (int xx = sx; xx < ex; ++xx) s += base[yy * 16 + xx];
  float a = s * ((1.0f / (float)(ey - sy)) * (1.0f / (float)(ex - sx)));
  ushort uh, um, ul;
  split3(a, &uh, &um, &ul);
  rh[(size_t)n * 32 + c] = uh;
  rm[(size_t)n * 32 + c] = um;
  rl[(size_t)n * 32 + c] = ul;
}

// last scale: transpose f_rest [b][c][256] -> [n][c] 3-level bf16
__global__ __launch_bounds__(256) void k_split(const float* __restrict__ fr,
                                               ushort* __restrict__ rh,
                                               ushort* __restrict__ rm,
                                               ushort* __restrict__ rl) {
  __shared__ float tile[8192];
  int b = blockIdx.x, t = threadIdx.x;
  const float4* src = (const float4*)(fr + (size_t)b * 8192);
  float4* t4 = (float4*)tile;
  for (int i = t; i < 2048; i += 256) t4[i] = src[i];
  __syncthreads();
  size_t n = (size_t)b * 256 + t;
  for (int c0 = 0; c0 < 32; c0 += 8) {
    ushort hs[8], ms[8], ls[8];
#pragma unroll
    for (int j = 0; j < 8; ++j) split3(tile[(c0 + j) * 256 + t], &hs[j], &ms[j], &ls[j]);
    uint4 ph, pm, pl;
    ph.x = (unsigned)hs[0] | ((unsigned)hs[1] << 16); ph.y = (unsigned)hs[2] | ((unsigned)hs[3] << 16);
    ph.z = (unsigned)hs[4] | ((unsigned)hs[5] << 16); ph.w = (unsigned)hs[6] | ((unsigned)hs[7] << 16);
    pm.x = (unsigned)ms[0] | ((unsigned)ms[1] << 16); pm.y = (unsigned)ms[2] | ((unsigned)ms[3] << 16);
    pm.z = (unsigned)ms[4] | ((unsigned)ms[5] << 16); pm.w = (unsigned)ms[6] | ((unsigned)ms[7] << 16);
    pl.x = (unsigned)ls[0] | ((unsigned)ls[1] << 16); pl.y = (unsigned)ls[2] | ((unsigned)ls[3] << 16);
    pl.z = (unsigned)ls[4] | ((unsigned)ls[5] << 16); pl.w = (unsigned)ls[6] | ((unsigned)ls[7] << 16);
    *(uint4*)(rh + n * 32 + c0) = ph;
    *(uint4*)(rm + n * 32 + c0) = pm;
    *(uint4*)(rl + n * 32 + c0) = pl;
  }
}

// MFMA NN search. Block: 4 waves x R row-tiles of 16 rows. grid (rowblocks, S).
// Maximizes m = dot - esq/2  (== argmin distance). Writes per-split partials.
template<int R>
__global__ __launch_bounds__(256) void k_nn(const ushort* __restrict__ rest_h,
                                            const ushort* __restrict__ rest_m,
                                            const ushort* __restrict__ rest_l,
                                            const ushort* __restrict__ emb_h,
                                            const ushort* __restrict__ emb_m,
                                            const ushort* __restrict__ emb_l,
                                            const float* __restrict__ esq_g,
                                            float* __restrict__ pdist,
                                            int* __restrict__ pidx,
                                            int rows, int S, int cps) {
  __shared__ ushort lb[2][3][2048];   // [buf][level][slot*8]
  __shared__ float les[2][64];
  const int t = threadIdx.x;
  const int w = t >> 6;
  const int col = t & 15;
  const int g = (t >> 4) & 3;
  const int sp = blockIdx.y;
  const int rowbase = blockIdx.x * (64 * R);

  // A fragments in registers (3 levels x R row-tiles)
  short8_t ah[R], am[R], al[R];
#pragma unroll
  for (int rt = 0; rt < R; ++rt) {
    int n = rowbase + (w * R + rt) * 16 + col;
    if (n >= rows) n = rows - 1;
    size_t o = (size_t)n * 32 + g * 8;
    ah[rt] = *(const short8_t*)(rest_h + o);
    am[rt] = *(const short8_t*)(rest_m + o);
    al[rt] = *(const short8_t*)(rest_l + o);
  }

  float best[R][4];
  int bidx[R][4];
#pragma unroll
  for (int rt = 0; rt < R; ++rt)
#pragma unroll
    for (int r = 0; r < 4; ++r) { best[rt][r] = -3.4e38f; bidx[rt][r] = 0x7fffffff; }

  auto stage = [&](int bf, int ch) {
    int cb = sp * cps + ch * 64;
    int code = cb + (t >> 2);
    int u = (t & 3) ^ ((code ^ (code >> 2)) & 3);
    size_t off = (size_t)code * 32 + (size_t)u * 8;
    gl_lds16(emb_h + off, &lb[bf][0][w * 512]);
    gl_lds16(emb_m + off, &lb[bf][1][w * 512]);
    gl_lds16(emb_l + off, &lb[bf][2][w * 512]);
    if ((t & 63) < 16) gl_lds4(esq_g + cb + w * 16 + (t & 15), &les[bf][w * 16]);
  };

  const int NC = cps >> 6;
  stage(0, 0);
  int buf = 0;
  for (int ch = 0; ch < NC; ++ch) {
    if (ch + 1 < NC) {
      stage(buf ^ 1, ch + 1);
      asm volatile("s_waitcnt vmcnt(4)" ::: "memory");
    } else {
      asm volatile("s_waitcnt vmcnt(0)" ::: "memory");
    }
    __builtin_amdgcn_s_barrier();

    int cb0 = sp * cps + ch * 64;
#pragma unroll
    for (int s4 = 0; s4 < 4; ++s4) {
      int cl = s4 * 16 + col;
      int slotbase = (cl * 4 + (g ^ ((cl ^ (cl >> 2)) & 3))) * 8;
      short8_t bh  = *(const short8_t*)&lb[buf][0][slotbase];
      short8_t bm  = *(const short8_t*)&lb[buf][1][slotbase];
      short8_t bl2 = *(const short8_t*)&lb[buf][2][slotbase];
      float es = les[buf][cl];
      int code = cb0 + cl;
      f32x4 c0 = {-0.5f * es, -0.5f * es, -0.5f * es, -0.5f * es};
#pragma unroll
      for (int rt = 0; rt < R; ++rt) {
        f32x4 acc = c0;
        acc = MFMA(ah[rt], bh, acc);
        acc = MFMA(ah[rt], bm, acc);
        acc = MFMA(am[rt], bh, acc);
        acc = MFMA(ah[rt], bl2, acc);
        acc = MFMA(am[rt], bm, acc);
        acc = MFMA(al[rt], bh, acc);
#pragma unroll
        for (int r = 0; r < 4; ++r)
          if (acc[r] > best[rt][r]) { best[rt][r] = acc[r]; bidx[rt][r] = code; }
      }
    }
    __syncthreads();
    buf ^= 1;
  }

  // reduce across the 16 cols (lanes sharing a row-group), tie -> lowest idx
#pragma unroll
  for (int rt = 0; rt < R; ++rt)
#pragma unroll
    for (int r = 0; r < 4; ++r) {
      float bd = best[rt][r];
      int bi = bidx[rt][r];
#pragma unroll
      for (int mm = 1; mm < 16; mm <<= 1) {
        float od = __shfl_xor(bd, mm, 16);
        int oi = __shfl_xor(bi, mm, 16);
        if (od > bd || (od == bd && oi < bi)) { bd = od; bi = oi; }
      }
      if ((t & 15) == 0) {
        int rown = rowbase + (w * R + rt) * 16 + g * 4 + r;
        if (rown < rows) {
          pdist[(size_t)rown * S + sp] = bd;
          pidx[(size_t)rown * S + sp] = bi;
        }
      }
    }
}

// combine split-partials + gather emb rows into h_sm [b][c][rem]; write idx
__global__ __launch_bounds__(256) void k_cg(const float* __restrict__ pdist,
                                            const int* __restrict__ pidx,
                                            const float* __restrict__ emb,
                                            float* __restrict__ out_idx_f,
                                            float* __restrict__ h_sm,
                                            int rows, int S, int pn2) {
  int t = blockIdx.x * 256 + threadIdx.x;
  if (t >= rows * 8) return;
  int n = t >> 3, cq = t & 7;
  const float* pd = pdist + (size_t)n * S;
  const int* pi = pidx + (size_t)n * S;
  float bd = pd[0];
  int bi = pi[0];
  for (int s = 1; s < S; ++s) {
    float d = pd[s]; int i2 = pi[s];
    if (d > bd || (d == bd && i2 < bi)) { bd = d; bi = i2; }
  }
  if (cq == 0) out_idx_f[n] = (float)bi;
  int b = n / pn2, rem = n % pn2;
  float4 e = *(const float4*)(emb + (size_t)bi * 32 + cq * 4);
  float* dst = h_sm + ((size_t)b * 32 + cq * 4) * pn2 + rem;
  dst[0] = e.x; dst[(size_t)pn2] = e.y; dst[2 * (size_t)pn2] = e.z; dst[3 * (size_t)pn2] = e.w;
}

// bicubic upsample [B,C,pn,pn] -> [B,C,16,16]
__global__ __launch_bounds__(256) void k_up(const float* __restrict__ hs,
                                            float* __restrict__ hu,
                                            const float* __restrict__ tw,
                                            const int* __restrict__ ti,
                                            int pn, int si) {
  int tid = blockIdx.x * 256 + threadIdx.x;
  int X = tid & 15, Y = (tid >> 4) & 15;
  int bc = tid >> 8;
  const float* w = tw + si * 64;
  const int* ix = ti + si * 64;
  const float* src = hs + (size_t)bc * pn * pn;
  float wx[4]; int ixx[4];
#pragma unroll
  for (int u = 0; u < 4; ++u) { wx[u] = w[X * 4 + u]; ixx[u] = ix[X * 4 + u]; }
  float acc = 0.f;
#pragma unroll
  for (int tt = 0; tt < 4; ++tt) {
    float wy = w[Y * 4 + tt];
    int iy = ix[Y * 4 + tt];
    const float* rowp = src + iy * pn;
    float r = 0.f;
#pragma unroll
    for (int u = 0; u < 4; ++u) r += wx[u] * rowp[ixx[u]];
    acc += wy * r;
  }
  hu[tid] = acc;
}

// 3x3 conv + residual mix; fused f_hat += / f_rest -= and per-block loss partial
__global__ __launch_bounds__(256) void k_conv(const float* __restrict__ h,
                                              const float* __restrict__ W,
                                              const float* __restrict__ bias,
                                              const float* __restrict__ f,
                                              float* __restrict__ f_hat,
                                              float* __restrict__ f_rest,
                                              float* __restrict__ lossp) {
  __shared__ float in_s[32 * 256];
  __shared__ float red[256];
  int b = blockIdx.x, cog = blockIdx.y * 8;
  int t = threadIdx.x;
  const float4* h4 = (const float4*)(h + (size_t)b * 32 * 256);
  float4* in4 = (float4*)in_s;
  for (int i = t; i < 32 * 64; i += 256) in4[i] = h4[i];
  __syncthreads();

  int X = t & 15, Y = t >> 4;
  float acc[8];
#pragma unroll
  for (int o = 0; o < 8; ++o) acc[o] = bias[cog + o];

  for (int ci = 0; ci < 32; ++ci) {
    float in9[9];
#pragma unroll
    for (int dy = 0; dy < 3; ++dy)
#pragma unroll
      for (int dx = 0; dx < 3; ++dx) {
        int yy = Y + dy - 1, xx = X + dx - 1;
        in9[dy * 3 + dx] = (yy >= 0 && yy < 16 && xx >= 0 && xx < 16)
                               ? in_s[ci * 256 + yy * 16 + xx] : 0.f;
      }
    const float* wp = W + ((size_t)cog * 32 + ci) * 9;
#pragma unroll
    for (int o = 0; o < 8; ++o) {
      const float* w9 = wp + (size_t)o * 32 * 9;
#pragma unroll
      for (int q = 0; q < 9; ++q) acc[o] += w9[q] * in9[q];
    }
  }
  float lsum = 0.f;
#pragma unroll
  for (int o = 0; o < 8; ++o) {
    size_t oidx = ((size_t)b * 32 + cog + o) * 256 + t;
    float out = 0.5f * in_s[(cog + o) * 256 + t] + 0.5f * acc[o];
    float nf = f_hat[oidx] + out;
    f_hat[oidx] = nf;
    f_rest[oidx] -= out;
    float d = nf - f[oidx];
    lsum += d * d;
  }
  red[t] = lsum;
  __syncthreads();
  for (int o = 128; o > 0; o >>= 1) {
    if (t < o) red[t] += red[t + o];
    __syncthreads();
  }
  if (t == 0) lossp[blockIdx.y * 128 + blockIdx.x] = red[0];
}

__global__ __launch_bounds__(256) void k_copy(const float* __restrict__ f_hat,
                                              float* __restrict__ out) {
  int g = blockIdx.x * 256 + threadIdx.x;
  ((float4*)out)[g] = ((const float4*)f_hat)[g];
}

__global__ __launch_bounds__(256) void k_lossfin(const float* __restrict__ part,
                                                 float* __restrict__ out) {
  int t = threadIdx.x;
  float s = 0.f;
  for (int i = t; i < SN_ * 512; i += 256) s += part[i];
  __shared__ float red[256];
  red[t] = s;
  __syncthreads();
  for (int o = 128; o > 0; o >>= 1) {
    if (t < o) red[t] += red[t + o];
    __syncthreads();
  }
  if (t == 0) out[NPIX_] = red[0] * (1.25f / (10.0f * (float)NPIX_));
}

// --------------------------- host side -------------------------------------

static void compute_phi_k(int* ks) {
  const int K = 4;
  double start = 1.0 / (3.0 * K);
  double stop = 1.0 - 1.0 / (3.0 * K);
  double step = (stop - start) / (K - 1);
  double ticks[4];
  for (int i = 0; i < K; ++i) ticks[i] = (double)i * step + start;
  ticks[K - 1] = stop;
  for (int si = 0; si < SN_; ++si) {
    double x = (double)si / (SN_ - 1);
    int best = 0;
    double bd = fabs(ticks[0] - x);
    for (int i = 1; i < K; ++i) {
      double d = fabs(ticks[i] - x);
      if (d < bd) { bd = d; best = i; }
    }
    ks[si] = best;
  }
}

extern "C" void kernel_launch(void* const* d_in, const int* in_sizes, int n_in,
                              void* d_out, int out_size, void* d_ws, size_t ws_size,
                              hipStream_t stream) {
  (void)in_sizes; (void)n_in; (void)out_size; (void)ws_size;
  const float* f    = (const float*)d_in[0];
  const float* emb  = (const float*)d_in[1];
  const float* phiW = (const float*)d_in[2];
  const float* phiB = (const float*)d_in[3];
  float* out = (float*)d_out;
  float* ws = (float*)d_ws;

  float* f_rest = ws + WS_FREST;
  float* f_hat  = ws + WS_FHAT;
  float* h_sm   = ws + WS_HSM;
  float* h_up   = ws + WS_HUP;
  float* pdist  = ws + WS_HUP;               // aliased with h_up (disjoint in time)
  int*   pidx   = (int*)(ws + WS_HUP + 131072);
  float* esq    = ws + WS_ESQ;
  float* tw     = ws + WS_TW;
  int*   ti     = (int*)(ws + WS_TI);
  float* lossp  = ws + WS_LOSSP;
  ushort* rest_h = (ushort*)(ws + WS_RESTH);
  ushort* rest_m = (ushort*)(ws + WS_RESTM);
  ushort* rest_l = (ushort*)(ws + WS_RESTL);
  ushort* emb_h  = (ushort*)(ws + WS_EMBH);
  ushort* emb_m  = (ushort*)(ws + WS_EMBM);
  ushort* emb_l  = (ushort*)(ws + WS_EMBL);

  static const int pns[SN_] = {1, 2, 3, 4, 5, 6, 8, 10, 13, 16};
  static const int Rs[SN_]  = {1, 1, 1, 2, 2, 2, 4, 4, 4, 4};
  static const int Ss[SN_]  = {32, 16, 16, 16, 8, 8, 8, 4, 4, 2};
  int ks[SN_];
  compute_phi_k(ks);

  k_init<<<1024, 256, 0, stream>>>(f, f_rest, f_hat);
  k_esplit<<<16, 256, 0, stream>>>(emb, esq, emb_h, emb_m, emb_l);
  k_taps<<<1, 256, 0, stream>>>(tw, ti);

  int idx_off = 0;
  for (int si = 0; si < SN_; ++si) {
    int pn = pns[si];
    int pn2 = pn * pn;
    int rows = B_ * pn2;
    int R = Rs[si], S = Ss[si];
    int cps = V_ / S;
    int rowblocks = (rows + 64 * R - 1) / (64 * R);

    if (si < SN_ - 1)
      k_down3<<<(rows * 32 + 255) / 256, 256, 0, stream>>>(f_rest, rest_h, rest_m, rest_l, pn, rows * 32);
    else
      k_split<<<128, 256, 0, stream>>>(f_rest, rest_h, rest_m, rest_l);

    dim3 grid(rowblocks, S);
    if (R == 1)
      k_nn<1><<<grid, 256, 0, stream>>>(rest_h, rest_m, rest_l, emb_h, emb_m, emb_l,
                                        esq, pdist, pidx, rows, S, cps);
    else if (R == 2)
      k_nn<2><<<grid, 256, 0, stream>>>(rest_h, rest_m, rest_l, emb_h, emb_m, emb_l,
                                        esq, pdist, pidx, rows, S, cps);
    else
      k_nn<4><<<grid, 256, 0, stream>>>(rest_h, rest_m, rest_l, emb_h, emb_m, emb_l,
                                        esq, pdist, pidx, rows, S, cps);

    k_cg<<<(rows * 8 + 255) / 256, 256, 0, stream>>>(pdist, pidx, emb,
                                                     out + NPIX_ + 1 + idx_off, h_sm, rows, S, pn2);

    if (si < SN_ - 1)
      k_up<<<NPIX_ / 256, 256, 0, stream>>>(h_sm, h_up, tw, ti, pn, si);

    const float* hin = (si < SN_ - 1) ? h_up : h_sm;
    k_conv<<<dim3(B_, 4), 256, 0, stream>>>(hin, phiW + (size_t)ks[si] * 32 * 32 * 9,
                                            phiB + (size_t)ks[si] * 32, f, f_hat, f_rest,
                                            lossp + si * 512);
    idx_off += rows;
  }

  k_copy<<<1024, 256, 0, stream>>>(f_hat, out);
  k_lossfin<<<1, 256, 0, stream>>>(lossp, out);
}

// Round 3
// 641.831 us; speedup vs baseline: 1.7483x; 1.1137x over previous
//
#include <hip/hip_runtime.h>
#include <hip/hip_bf16.h>
#include <math.h>

// ---------------------------------------------------------------------------
// VAR quantizer forward. Round 3: lc-outer/rt-inner MFMA ordering (independent
// accumulator chains), >=2 blocks/CU grids for k_nn, fused pooling into k_conv,
// fused combine+gather+bicubic (k_cgu), dispatch count 54 -> 34.
// Output: [f_hat 1048576][loss 1][idx-as-float 87040]
// ---------------------------------------------------------------------------

#define B_  128
#define C_  32
#define V_  4096
#define SN_ 10
#define NPIX_ (B_*C_*16*16)   // 1048576

// ws layout (float offsets)
#define WS_FREST   0
#define WS_FHAT    1048576
#define WS_HUP     2097152
#define WS_PD      3145728
#define WS_PI      3350528
#define WS_IDXI    3555328
#define WS_ESQ     3588096
#define WS_TW      3592192
#define WS_TI      3592768
#define WS_LOSSP   3593344
#define WS_RESTH   3598464
#define WS_RESTM   4122752
#define WS_RESTL   4647040
#define WS_EMBH    5171328
#define WS_EMBM    5236864
#define WS_EMBL    5302400
// end 5367936 floats = 20.5 MB

typedef __attribute__((ext_vector_type(8))) short short8_t;
typedef __attribute__((ext_vector_type(4))) float f32x4;
#define MFMA(a,b,c) __builtin_amdgcn_mfma_f32_16x16x32_bf16((a),(b),(c),0,0,0)

__device__ inline void gl_lds16(const void* g, void* l) {
  __builtin_amdgcn_global_load_lds((const __attribute__((address_space(1))) void*)g,
                                   (__attribute__((address_space(3))) void*)l, 16, 0, 0);
}
__device__ inline void gl_lds4(const void* g, void* l) {
  __builtin_amdgcn_global_load_lds((const __attribute__((address_space(1))) void*)g,
                                   (__attribute__((address_space(3))) void*)l, 4, 0, 0);
}

// split f32 -> 3 truncated bf16 levels (captures ~24 bits)
__device__ inline void split3(float a, ushort* h, ushort* m, ushort* l) {
  unsigned ua = __float_as_uint(a);
  ushort uh = (ushort)(ua >> 16);
  float fh = __uint_as_float((unsigned)uh << 16);
  float r1 = a - fh;
  ushort um = (ushort)(__float_as_uint(r1) >> 16);
  float fm = __uint_as_float((unsigned)um << 16);
  float r2 = r1 - fm;
  ushort ul = (ushort)(__float_as_uint(r2) >> 16);
  *h = uh; *m = um; *l = ul;
}

// --------------------------- init kernels ----------------------------------

__global__ __launch_bounds__(256) void k_init(const float* __restrict__ f,
                                              float* __restrict__ f_rest,
                                              float* __restrict__ f_hat) {
  int g = blockIdx.x * 256 + threadIdx.x;
  float4 v = ((const float4*)f)[g];
  ((float4*)f_rest)[g] = v;
  ((float4*)f_hat)[g] = make_float4(0.f, 0.f, 0.f, 0.f);
}

__global__ __launch_bounds__(256) void k_esplit(const float* __restrict__ emb,
                                                float* __restrict__ esq,
                                                ushort* __restrict__ eh,
                                                ushort* __restrict__ em,
                                                ushort* __restrict__ el) {
  int v = blockIdx.x * 256 + threadIdx.x;
  const float4* e4 = (const float4*)(emb + (size_t)v * 32);
  float s = 0.f;
#pragma unroll
  for (int half = 0; half < 4; ++half) {
    float4 x0 = e4[half * 2], x1 = e4[half * 2 + 1];
    s += x0.x * x0.x + x0.y * x0.y + x0.z * x0.z + x0.w * x0.w;
    s += x1.x * x1.x + x1.y * x1.y + x1.z * x1.z + x1.w * x1.w;
    float xs[8] = {x0.x, x0.y, x0.z, x0.w, x1.x, x1.y, x1.z, x1.w};
    ushort hs[8], ms[8], ls[8];
#pragma unroll
    for (int j = 0; j < 8; ++j) split3(xs[j], &hs[j], &ms[j], &ls[j]);
    uint4 ph, pm, pl;
    ph.x = (unsigned)hs[0] | ((unsigned)hs[1] << 16); ph.y = (unsigned)hs[2] | ((unsigned)hs[3] << 16);
    ph.z = (unsigned)hs[4] | ((unsigned)hs[5] << 16); ph.w = (unsigned)hs[6] | ((unsigned)hs[7] << 16);
    pm.x = (unsigned)ms[0] | ((unsigned)ms[1] << 16); pm.y = (unsigned)ms[2] | ((unsigned)ms[3] << 16);
    pm.z = (unsigned)ms[4] | ((unsigned)ms[5] << 16); pm.w = (unsigned)ms[6] | ((unsigned)ms[7] << 16);
    pl.x = (unsigned)ls[0] | ((unsigned)ls[1] << 16); pl.y = (unsigned)ls[2] | ((unsigned)ls[3] << 16);
    pl.z = (unsigned)ls[4] | ((unsigned)ls[5] << 16); pl.w = (unsigned)ls[6] | ((unsigned)ls[7] << 16);
    ((uint4*)(eh + (size_t)v * 32))[half] = ph;
    ((uint4*)(em + (size_t)v * 32))[half] = pm;
    ((uint4*)(el + (size_t)v * 32))[half] = pl;
  }
  esq[v] = s;
}

__global__ void k_taps(float* __restrict__ tw, int* __restrict__ ti) {
  int t = threadIdx.x;
  if (t >= 144) return;
  const int pns[9] = {1, 2, 3, 4, 5, 6, 8, 10, 13};
  int si = t / 16, Y = t % 16;
  int pn = pns[si];
  double src = (Y + 0.5) * (double)pn / 16.0 - 0.5;
  double fl = floor(src);
  const double a = -0.75;
#pragma unroll
  for (int k = 0; k < 4; ++k) {
    double x = fabs(src - (fl + (k - 1)));
    double w;
    if (x <= 1.0)      w = (a + 2.0) * x * x * x - (a + 3.0) * x * x + 1.0;
    else if (x < 2.0)  w = a * x * x * x - 5.0 * a * x * x + 8.0 * a * x - 4.0 * a;
    else               w = 0.0;
    int id = (int)fl + (k - 1);
    id = id < 0 ? 0 : (id > pn - 1 ? pn - 1 : id);
    tw[si * 64 + Y * 4 + k] = (float)w;
    ti[si * 64 + Y * 4 + k] = id;
  }
}

// initial area downsample (si=0) from f: [b][c][256] -> [n][c] 3-level bf16
__global__ __launch_bounds__(256) void k_down3(const float* __restrict__ fr,
                                               ushort* __restrict__ rh,
                                               ushort* __restrict__ rm,
                                               ushort* __restrict__ rl,
                                               int pn, int total) {
  int tid = blockIdx.x * 256 + threadIdx.x;
  if (tid >= total) return;
  int c = tid & 31, n = tid >> 5;
  int pn2 = pn * pn;
  int b = n / pn2, rem = n % pn2;
  int y = rem / pn, x = rem % pn;
  int sy = (y * 16) / pn, ey = ((y + 1) * 16 + pn - 1) / pn;
  int sx = (x * 16) / pn, ex = ((x + 1) * 16 + pn - 1) / pn;
  const float* base = fr + ((size_t)b * 32 + c) * 256;
  float s = 0.f;
  for (int yy = sy; yy < ey; ++yy)
    for (int xx = sx; xx < ex; ++xx) s += base[yy * 16 + xx];
  float a = s * ((1.0f / (float)(ey - sy)) * (1.0f / (float)(ex - sx)));
  ushort uh, um, ul;
  split3(a, &uh, &um, &ul);
  rh[(size_t)n * 32 + c] = uh;
  rm[(size_t)n * 32 + c] = um;
  rl[(size_t)n * 32 + c] = ul;
}

// --------------------------- NN search -------------------------------------
// Block: 4 waves x R row-tiles of 16 rows vs 64-code tiles; lc-outer/rt-inner
// gives R independent MFMA chains. Maximizes dot - esq/2 (== argmin distance).
template<int R>
__global__ __launch_bounds__(256) void k_nn(const ushort* __restrict__ rest_h,
                                            const ushort* __restrict__ rest_m,
                                            const ushort* __restrict__ rest_l,
                                            const ushort* __restrict__ emb_h,
                                            const ushort* __restrict__ emb_m,
                                            const ushort* __restrict__ emb_l,
                                            const float* __restrict__ esq_g,
                                            float* __restrict__ pdist,
                                            int* __restrict__ pidx,
                                            int rows, int S, int cps) {
  __shared__ ushort lb[2][3][2048];
  __shared__ float les[2][64];
  const int t = threadIdx.x;
  const int w = t >> 6;
  const int col = t & 15;
  const int g = (t >> 4) & 3;
  const int sp = blockIdx.y;
  const int rowbase = blockIdx.x * (64 * R);

  auto stage = [&](int bf, int ch) {
    int cb = sp * cps + ch * 64;
    int code = cb + (t >> 2);
    int u = (t & 3) ^ ((code ^ (code >> 2)) & 3);
    size_t off = (size_t)code * 32 + (size_t)u * 8;
    gl_lds16(emb_h + off, &lb[bf][0][w * 512]);
    gl_lds16(emb_m + off, &lb[bf][1][w * 512]);
    gl_lds16(emb_l + off, &lb[bf][2][w * 512]);
    if ((t & 63) < 16) gl_lds4(esq_g + cb + w * 16 + (t & 15), &les[bf][w * 16]);
  };

  stage(0, 0);

  // A fragments in registers (3 levels x R row-tiles)
  short8_t ah[R], am[R], al[R];
#pragma unroll
  for (int rt = 0; rt < R; ++rt) {
    int n = rowbase + (w * R + rt) * 16 + col;
    if (n >= rows) n = rows - 1;
    size_t o = (size_t)n * 32 + g * 8;
    ah[rt] = *(const short8_t*)(rest_h + o);
    am[rt] = *(const short8_t*)(rest_m + o);
    al[rt] = *(const short8_t*)(rest_l + o);
  }

  float best[R][4];
  int bidx[R][4];
#pragma unroll
  for (int rt = 0; rt < R; ++rt)
#pragma unroll
    for (int r = 0; r < 4; ++r) { best[rt][r] = -3.4e38f; bidx[rt][r] = 0x7fffffff; }

  const int NC = cps >> 6;
  int buf = 0;
  for (int ch = 0; ch < NC; ++ch) {
    if (ch + 1 < NC) {
      stage(buf ^ 1, ch + 1);
      asm volatile("s_waitcnt vmcnt(4)" ::: "memory");
    } else {
      asm volatile("s_waitcnt vmcnt(0)" ::: "memory");
    }
    __builtin_amdgcn_s_barrier();

    int cb0 = sp * cps + ch * 64;
#pragma unroll
    for (int s4 = 0; s4 < 4; ++s4) {
      int cl = s4 * 16 + col;
      int slotbase = (cl * 4 + (g ^ ((cl ^ (cl >> 2)) & 3))) * 8;
      short8_t bh  = *(const short8_t*)&lb[buf][0][slotbase];
      short8_t bm  = *(const short8_t*)&lb[buf][1][slotbase];
      short8_t bl2 = *(const short8_t*)&lb[buf][2][slotbase];
      float es = les[buf][cl];
      f32x4 c0 = {-0.5f * es, -0.5f * es, -0.5f * es, -0.5f * es};
      f32x4 acc[R];
      // same per-acc order as round 2 (bitwise identical): hh,hm,mh,hl,mm,lh
#pragma unroll
      for (int rt = 0; rt < R; ++rt) acc[rt] = MFMA(ah[rt], bh, c0);
#pragma unroll
      for (int rt = 0; rt < R; ++rt) acc[rt] = MFMA(ah[rt], bm, acc[rt]);
#pragma unroll
      for (int rt = 0; rt < R; ++rt) acc[rt] = MFMA(am[rt], bh, acc[rt]);
#pragma unroll
      for (int rt = 0; rt < R; ++rt) acc[rt] = MFMA(ah[rt], bl2, acc[rt]);
#pragma unroll
      for (int rt = 0; rt < R; ++rt) acc[rt] = MFMA(am[rt], bm, acc[rt]);
#pragma unroll
      for (int rt = 0; rt < R; ++rt) acc[rt] = MFMA(al[rt], bh, acc[rt]);
      int code = cb0 + cl;
#pragma unroll
      for (int rt = 0; rt < R; ++rt)
#pragma unroll
        for (int r = 0; r < 4; ++r)
          if (acc[rt][r] > best[rt][r]) { best[rt][r] = acc[rt][r]; bidx[rt][r] = code; }
    }
    __syncthreads();
    buf ^= 1;
  }

#pragma unroll
  for (int rt = 0; rt < R; ++rt)
#pragma unroll
    for (int r = 0; r < 4; ++r) {
      float bd = best[rt][r];
      int bi = bidx[rt][r];
#pragma unroll
      for (int mm2 = 1; mm2 < 16; mm2 <<= 1) {
        float od = __shfl_xor(bd, mm2, 16);
        int oi = __shfl_xor(bi, mm2, 16);
        if (od > bd || (od == bd && oi < bi)) { bd = od; bi = oi; }
      }
      if ((t & 15) == 0) {
        int rown = rowbase + (w * R + rt) * 16 + g * 4 + r;
        if (rown < rows) {
          pdist[(size_t)rown * S + sp] = bd;
          pidx[(size_t)rown * S + sp] = bi;
        }
      }
    }
}

// --------------------------- combine/gather/upsample ------------------------

// si<=8: one block per b. combine split partials -> idx; gather emb to LDS;
// bicubic upsample to h_up [b][32][256].
__global__ __launch_bounds__(256) void k_cgu(const float* __restrict__ pdist,
                                             const int* __restrict__ pidx,
                                             const float* __restrict__ emb,
                                             const float* __restrict__ tw,
                                             const int* __restrict__ ti,
                                             float* __restrict__ out_idx_f,
                                             float* __restrict__ h_up,
                                             int S, int pn, int si) {
  __shared__ int ci_s[256];
  __shared__ float hsm[32][176];
  int b = blockIdx.x, t = threadIdx.x;
  int pn2 = pn * pn;
  for (int rem = t; rem < pn2; rem += 256) {
    int n = b * pn2 + rem;
    const float* pd = pdist + (size_t)n * S;
    const int* pi = pidx + (size_t)n * S;
    float bd = pd[0];
    int bi = pi[0];
    for (int s = 1; s < S; ++s) {
      float d = pd[s]; int i2 = pi[s];
      if (d > bd || (d == bd && i2 < bi)) { bd = d; bi = i2; }
    }
    out_idx_f[n] = (float)bi;
    ci_s[rem] = bi;
  }
  __syncthreads();
  {
    int c = t & 31;
    for (int rem0 = t >> 5; rem0 < pn2; rem0 += 8)
      hsm[c][rem0] = emb[(size_t)ci_s[rem0] * 32 + c];
  }
  __syncthreads();
  int X = t & 15, Y = t >> 4;
  float wx[4], wy[4]; int ixx[4], iyy[4];
#pragma unroll
  for (int u = 0; u < 4; ++u) {
    wx[u] = tw[si * 64 + X * 4 + u]; ixx[u] = ti[si * 64 + X * 4 + u];
    wy[u] = tw[si * 64 + Y * 4 + u]; iyy[u] = ti[si * 64 + Y * 4 + u];
  }
  for (int c = 0; c < 32; ++c) {
    float acc = 0.f;
#pragma unroll
    for (int tt2 = 0; tt2 < 4; ++tt2) {
      const float* rowp = &hsm[c][iyy[tt2] * pn];
      float r = 0.f;
#pragma unroll
      for (int u = 0; u < 4; ++u) r += wx[u] * rowp[ixx[u]];
      acc += wy[tt2] * r;
    }
    h_up[((size_t)b * 32 + c) * 256 + t] = acc;
  }
}

// si=9: combine only -> out idx (float) + int idx for k_conv gather
__global__ __launch_bounds__(256) void k_comb(const float* __restrict__ pdist,
                                              const int* __restrict__ pidx,
                                              int rows, int S,
                                              float* __restrict__ out_idx_f,
                                              int* __restrict__ idxint) {
  int n = blockIdx.x * 256 + threadIdx.x;
  if (n >= rows) return;
  const float* pd = pdist + (size_t)n * S;
  const int* pi = pidx + (size_t)n * S;
  float bd = pd[0];
  int bi = pi[0];
  for (int s = 1; s < S; ++s) {
    float d = pd[s]; int i2 = pi[s];
    if (d > bd || (d == bd && i2 < bi)) { bd = d; bi = i2; }
  }
  out_idx_f[n] = (float)bi;
  idxint[n] = bi;
}

// --------------------------- conv + residual + pooling ----------------------
// grid (B,4): 8 out-channels per block. Fused: loss partial, f_hat/f_rest
// update, area-pool+split3 for next scale's NN input, optional final out.
__global__ __launch_bounds__(256) void k_conv(const float* __restrict__ h,
                                              const int* __restrict__ gidx,
                                              const float* __restrict__ emb,
                                              const float* __restrict__ W,
                                              const float* __restrict__ bias,
                                              const float* __restrict__ f,
                                              float* __restrict__ f_hat,
                                              float* __restrict__ f_rest,
                                              float* __restrict__ lossp,
                                              float* __restrict__ final_out,
                                              ushort* __restrict__ rh,
                                              ushort* __restrict__ rm,
                                              ushort* __restrict__ rl,
                                              int pn_next) {
  __shared__ float in_s[32 * 256];
  __shared__ float red[256];
  int b = blockIdx.x, cog = blockIdx.y * 8;
  int t = threadIdx.x;
  if (gidx) {
    int code = gidx[b * 256 + t];
    const float4* er = (const float4*)(emb + (size_t)code * 32);
#pragma unroll
    for (int q = 0; q < 8; ++q) {
      float4 e = er[q];
      in_s[(q * 4 + 0) * 256 + t] = e.x;
      in_s[(q * 4 + 1) * 256 + t] = e.y;
      in_s[(q * 4 + 2) * 256 + t] = e.z;
      in_s[(q * 4 + 3) * 256 + t] = e.w;
    }
  } else {
    const float4* h4 = (const float4*)(h + (size_t)b * 8192);
    float4* in4 = (float4*)in_s;
    for (int i = t; i < 2048; i += 256) in4[i] = h4[i];
  }
  __syncthreads();

  int X = t & 15, Y = t >> 4;
  float acc[8];
#pragma unroll
  for (int o = 0; o < 8; ++o) acc[o] = bias[cog + o];

  for (int ci = 0; ci < 32; ++ci) {
    float in9[9];
#pragma unroll
    for (int dy = 0; dy < 3; ++dy)
#pragma unroll
      for (int dx = 0; dx < 3; ++dx) {
        int yy = Y + dy - 1, xx = X + dx - 1;
        in9[dy * 3 + dx] = (yy >= 0 && yy < 16 && xx >= 0 && xx < 16)
                               ? in_s[ci * 256 + yy * 16 + xx] : 0.f;
      }
    const float* wp = W + ((size_t)cog * 32 + ci) * 9;
#pragma unroll
    for (int o = 0; o < 8; ++o) {
      const float* w9 = wp + (size_t)o * 32 * 9;
#pragma unroll
      for (int q = 0; q < 9; ++q) acc[o] += w9[q] * in9[q];
    }
  }

  float lsum = 0.f;
  float nr[8];
#pragma unroll
  for (int o = 0; o < 8; ++o) {
    size_t oidx = ((size_t)b * 32 + cog + o) * 256 + t;
    float out = 0.5f * in_s[(cog + o) * 256 + t] + 0.5f * acc[o];
    float nf = f_hat[oidx] + out;
    if (final_out) final_out[oidx] = nf;
    else f_hat[oidx] = nf;
    if (pn_next > 0) {
      float fr = f_rest[oidx] - out;
      f_rest[oidx] = fr;
      nr[o] = fr;
    }
    float d = nf - f[oidx];
    lsum += d * d;
  }
  red[t] = lsum;
  __syncthreads();
  for (int o = 128; o > 0; o >>= 1) {
    if (t < o) red[t] += red[t + o];
    __syncthreads();
  }
  if (t == 0) lossp[blockIdx.y * 128 + blockIdx.x] = red[0];

  if (pn_next > 0) {
    // reuse in_s[0..2047] for the 8 updated-residual channel maps
    __syncthreads();
#pragma unroll
    for (int o = 0; o < 8; ++o) in_s[o * 256 + t] = nr[o];
    __syncthreads();
    int pn2 = pn_next * pn_next;
    for (int i = t; i < 8 * pn2; i += 256) {
      int o = i / pn2, rem = i - o * pn2;
      int y = rem / pn_next, x = rem - y * pn_next;
      int sy = (y * 16) / pn_next, ey = ((y + 1) * 16 + pn_next - 1) / pn_next;
      int sx = (x * 16) / pn_next, ex = ((x + 1) * 16 + pn_next - 1) / pn_next;
      float s = 0.f;
      for (int yy = sy; yy < ey; ++yy)
        for (int xx = sx; xx < ex; ++xx) s += in_s[o * 256 + yy * 16 + xx];
      float a = s * ((1.0f / (float)(ey - sy)) * (1.0f / (float)(ex - sx)));
      ushort uh, um, ul;
      split3(a, &uh, &um, &ul);
      size_t n = (size_t)b * pn2 + rem;
      rh[n * 32 + cog + o] = uh;
      rm[n * 32 + cog + o] = um;
      rl[n * 32 + cog + o] = ul;
    }
  }
}

__global__ __launch_bounds__(256) void k_lossfin(const float* __restrict__ part,
                                                 float* __restrict__ out) {
  int t = threadIdx.x;
  float s = 0.f;
  for (int i = t; i < SN_ * 512; i += 256) s += part[i];
  __shared__ float red[256];
  red[t] = s;
  __syncthreads();
  for (int o = 128; o > 0; o >>= 1) {
    if (t < o) red[t] += red[t + o];
    __syncthreads();
  }
  if (t == 0) out[NPIX_] = red[0] * (1.25f / (10.0f * (float)NPIX_));
}

// --------------------------- host side -------------------------------------

static void compute_phi_k(int* ks) {
  const int K = 4;
  double start = 1.0 / (3.0 * K);
  double stop = 1.0 - 1.0 / (3.0 * K);
  double step = (stop - start) / (K - 1);
  double ticks[4];
  for (int i = 0; i < K; ++i) ticks[i] = (double)i * step + start;
  ticks[K - 1] = stop;
  for (int si = 0; si < SN_; ++si) {
    double x = (double)si / (SN_ - 1);
    int best = 0;
    double bd = fabs(ticks[0] - x);
    for (int i = 1; i < K; ++i) {
      double d = fabs(ticks[i] - x);
      if (d < bd) { bd = d; best = i; }
    }
    ks[si] = best;
  }
}

extern "C" void kernel_launch(void* const* d_in, const int* in_sizes, int n_in,
                              void* d_out, int out_size, void* d_ws, size_t ws_size,
                              hipStream_t stream) {
  (void)in_sizes; (void)n_in; (void)out_size; (void)ws_size;
  const float* f    = (const float*)d_in[0];
  const float* emb  = (const float*)d_in[1];
  const float* phiW = (const float*)d_in[2];
  const float* phiB = (const float*)d_in[3];
  float* out = (float*)d_out;
  float* ws = (float*)d_ws;

  float* f_rest = ws + WS_FREST;
  float* f_hat  = ws + WS_FHAT;
  float* h_up   = ws + WS_HUP;
  float* pdist  = ws + WS_PD;
  int*   pidx   = (int*)(ws + WS_PI);
  int*   idxi   = (int*)(ws + WS_IDXI);
  float* esq    = ws + WS_ESQ;
  float* tw     = ws + WS_TW;
  int*   ti     = (int*)(ws + WS_TI);
  float* lossp  = ws + WS_LOSSP;
  ushort* rest_h = (ushort*)(ws + WS_RESTH);
  ushort* rest_m = (ushort*)(ws + WS_RESTM);
  ushort* rest_l = (ushort*)(ws + WS_RESTL);
  ushort* emb_h  = (ushort*)(ws + WS_EMBH);
  ushort* emb_m  = (ushort*)(ws + WS_EMBM);
  ushort* emb_l  = (ushort*)(ws + WS_EMBL);

  static const int pns[SN_] = {1, 2, 3, 4, 5, 6, 8, 10, 13, 16};
  static const int Rs[SN_]  = {1, 1, 1, 2, 2, 2, 4, 4, 4, 4};
  static const int Ss[SN_]  = {64, 64, 32, 32, 16, 16, 16, 16, 8, 4};
  int ks[SN_];
  compute_phi_k(ks);

  k_init<<<1024, 256, 0, stream>>>(f, f_rest, f_hat);
  k_esplit<<<16, 256, 0, stream>>>(emb, esq, emb_h, emb_m, emb_l);
  k_taps<<<1, 256, 0, stream>>>(tw, ti);
  // si=0 NN input comes straight from f (f_rest == f here)
  k_down3<<<16, 256, 0, stream>>>(f, rest_h, rest_m, rest_l, 1, 4096);

  int idx_off = 0;
  for (int si = 0; si < SN_; ++si) {
    int pn = pns[si];
    int pn2 = pn * pn;
    int rows = B_ * pn2;
    int R = Rs[si], S = Ss[si];
    int cps = V_ / S;
    int rowblocks = (rows + 64 * R - 1) / (64 * R);

    dim3 grid(rowblocks, S);
    if (R == 1)
      k_nn<1><<<grid, 256, 0, stream>>>(rest_h, rest_m, rest_l, emb_h, emb_m, emb_l,
                                        esq, pdist, pidx, rows, S, cps);
    else if (R == 2)
      k_nn<2><<<grid, 256, 0, stream>>>(rest_h, rest_m, rest_l, emb_h, emb_m, emb_l,
                                        esq, pdist, pidx, rows, S, cps);
    else
      k_nn<4><<<grid, 256, 0, stream>>>(rest_h, rest_m, rest_l, emb_h, emb_m, emb_l,
                                        esq, pdist, pidx, rows, S, cps);

    if (si < SN_ - 1)
      k_cgu<<<B_, 256, 0, stream>>>(pdist, pidx, emb, tw, ti,
                                    out + NPIX_ + 1 + idx_off, h_up, S, pn, si);
    else
      k_comb<<<(rows + 255) / 256, 256, 0, stream>>>(pdist, pidx, rows, S,
                                                     out + NPIX_ + 1 + idx_off, idxi);

    int pn_next = (si < SN_ - 1) ? pns[si + 1] : 0;
    k_conv<<<dim3(B_, 4), 256, 0, stream>>>(h_up,
                                            (si == SN_ - 1) ? idxi : (const int*)nullptr,
                                            emb,
                                            phiW + (size_t)ks[si] * 32 * 32 * 9,
                                            phiB + (size_t)ks[si] * 32,
                                            f, f_hat, f_rest,
                                            lossp + si * 512,
                                            (si == SN_ - 1) ? out : (float*)nullptr,
                                            rest_h, rest_m, rest_l, pn_next);
    idx_off += rows;
  }

  k_lossfin<<<1, 256, 0, stream>>>(lossp, out);
}